// Round 6
// baseline (105.885 us; speedup 1.0000x reference)
//
#include <hip/hip_runtime.h>

#define BB 16
#define NN 4096
#define CC 6
#define NSEG (BB * NN)          // 65536 rows per direction
#define JSP 16
#define JPB (NN / JSP)          // 256 j per block
#define IPT 8                   // rows per thread (4 packed pairs)
#define NPR (IPT / 2)
#define ISPLIT 2                // row split -> 1024 blocks, 4 waves/SIMD

typedef __attribute__((ext_vector_type(2))) float f32x2;

// part layout: float part[2][JSP][BB][NN] — partial row-mins (rx + min_t)

__global__ __launch_bounds__(256) void chamfer_min_kernel(
    const float* __restrict__ xg, const float* __restrict__ yg,
    float* __restrict__ part, float* __restrict__ out)
{
    const int bid = blockIdx.x;
    const int dir = bid & 1;
    const int jsp = (bid >> 1) & (JSP - 1);
    const int isp = (bid >> 5) & (ISPLIT - 1);
    const int b   = bid >> 6;

    const float* __restrict__ X = dir ? yg : xg;   // rows we take the min FOR
    const float* __restrict__ Y = dir ? xg : yg;   // points we min OVER
    const int tid = threadIdx.x;
    const size_t xb = (size_t)b * NN;

    if (bid == 0 && tid == 0) out[0] = 0.0f;       // replaces memset dispatch

    __shared__ float4 ytile[JPB];                  // (-2y0, -2y1, -2y2, ry)
    {
        const int j = jsp * JPB + tid;
        const float y0 = Y[(xb + j) * CC + 0];
        const float y1 = Y[(xb + j) * CC + 1];
        const float y2 = Y[(xb + j) * CC + 2];
        ytile[tid] = make_float4(-2.f * y0, -2.f * y1, -2.f * y2,
                                 fmaf(y0, y0, fmaf(y1, y1, y2 * y2)));
    }

    // rows packed in pairs: pair p holds rows (2p)*256+tid and (2p+1)*256+tid
    f32x2 x0p[NPR], x1p[NPR], x2p[NPR];
    float rx[IPT], m[IPT];
    #pragma unroll
    for (int r = 0; r < IPT; ++r) {
        const int i = isp * (IPT * 256) + r * 256 + tid;
        const float2 c01 = *(const float2*)&X[(xb + i) * CC];
        const float  c2  = X[(xb + i) * CC + 2];
        rx[r] = fmaf(c01.x, c01.x, fmaf(c01.y, c01.y, c2 * c2));
        m[r]  = 3.4e38f;
        const int p = r >> 1;
        if ((r & 1) == 0) { x0p[p].x = c01.x; x1p[p].x = c01.y; x2p[p].x = c2; }
        else              { x0p[p].y = c01.x; x1p[p].y = c01.y; x2p[p].y = c2; }
    }
    __syncthreads();   // tile staged once; only barrier

    float4 ya = ytile[0], yb = ytile[1];           // register double-buffer
    for (int js = 0; js < JPB; js += 2) {
        const float4 yc = ytile[(js + 2) & (JPB - 1)];   // prefetch next pair
        const float4 yd = ytile[(js + 3) & (JPB - 1)];
        const f32x2 Aa = {ya.x, ya.y}, Ba = {ya.z, ya.w};   // (y0',y1'), (y2',ry)
        const f32x2 Ab = {yb.x, yb.y}, Bb = {yb.z, yb.w};
        #pragma unroll
        for (int p = 0; p < NPR; ++p) {
            f32x2 ta, tb;
            // ta = x2p*bcast(y2') + bcast(ry)
            asm("v_pk_fma_f32 %0, %1, %2, %2 op_sel:[0,0,1] op_sel_hi:[1,0,1]"
                : "=v"(ta) : "v"(x2p[p]), "v"(Ba));
            asm("v_pk_fma_f32 %0, %1, %2, %3 op_sel:[0,1,0] op_sel_hi:[1,1,1]"
                : "=v"(ta) : "v"(x1p[p]), "v"(Aa), "0"(ta));
            asm("v_pk_fma_f32 %0, %1, %2, %3 op_sel:[0,0,0] op_sel_hi:[1,0,1]"
                : "=v"(ta) : "v"(x0p[p]), "v"(Aa), "0"(ta));

            asm("v_pk_fma_f32 %0, %1, %2, %2 op_sel:[0,0,1] op_sel_hi:[1,0,1]"
                : "=v"(tb) : "v"(x2p[p]), "v"(Bb));
            asm("v_pk_fma_f32 %0, %1, %2, %3 op_sel:[0,1,0] op_sel_hi:[1,1,1]"
                : "=v"(tb) : "v"(x1p[p]), "v"(Ab), "0"(tb));
            asm("v_pk_fma_f32 %0, %1, %2, %3 op_sel:[0,0,0] op_sel_hi:[1,0,1]"
                : "=v"(tb) : "v"(x0p[p]), "v"(Ab), "0"(tb));

            m[2*p]   = fminf(m[2*p],   fminf(ta.x, tb.x));   // -> v_min3_f32
            m[2*p+1] = fminf(m[2*p+1], fminf(ta.y, tb.y));   // -> v_min3_f32
        }
        ya = yc; yb = yd;
    }

    float* __restrict__ dst = part + ((size_t)(dir * JSP + jsp) * BB + b) * NN;
    #pragma unroll
    for (int r = 0; r < IPT; ++r)
        dst[isp * (IPT * 256) + r * 256 + tid] = rx[r] + m[r];
}

__global__ __launch_bounds__(256) void chamfer_reduce_kernel(
    const float* __restrict__ part, float* __restrict__ out)
{
    float s = 0.0f;
    for (int p = blockIdx.x * 256 + threadIdx.x; p < 2 * NSEG; p += 256 * 256) {
        const int dir = p >> 16;
        const int rem = p & (NSEG - 1);
        const float* base = part + (size_t)dir * JSP * NSEG + rem;
        float v = base[0];
        #pragma unroll
        for (int sg = 1; sg < JSP; ++sg)
            v = fminf(v, base[(size_t)sg * NSEG]);
        s += v;
    }

    for (int off = 32; off > 0; off >>= 1)
        s += __shfl_down(s, off, 64);

    __shared__ float wsum[4];
    const int wave = threadIdx.x >> 6;
    if ((threadIdx.x & 63) == 0) wsum[wave] = s;
    __syncthreads();
    if (threadIdx.x == 0)
        atomicAdd(out, (wsum[0] + wsum[1] + wsum[2] + wsum[3]) * (1.0f / NSEG));
}

extern "C" void kernel_launch(void* const* d_in, const int* in_sizes, int n_in,
                              void* d_out, int out_size, void* d_ws, size_t ws_size,
                              hipStream_t stream) {
    const float* x = (const float*)d_in[0];
    const float* y = (const float*)d_in[1];
    float* out = (float*)d_out;
    float* part = (float*)d_ws;   // needs 2*16*65536*4 = 8.4 MB (ws is ~265 MB)

    const int nblocks = 2 * JSP * ISPLIT * BB;   // 1024
    chamfer_min_kernel<<<nblocks, 256, 0, stream>>>(x, y, part, out);
    chamfer_reduce_kernel<<<256, 256, 0, stream>>>(part, out);
}